// Round 10
// baseline (995.249 us; speedup 1.0000x reference)
//
#include <hip/hip_runtime.h>
#include <hip/hip_bf16.h>

#define DIM 256
#define HEADS 4
#define NEG_SLOPE 0.01f

typedef unsigned short u16;
typedef __attribute__((ext_vector_type(8))) short short8;
typedef __attribute__((ext_vector_type(4))) float f32x4;
typedef __attribute__((ext_vector_type(4))) unsigned short u16x4;

// ---- bf16 helpers ----
__device__ __forceinline__ u16 f2bf(float f) {           // RTN-even
    unsigned u = __float_as_uint(f);
    unsigned r = (u + 0x7fffu + ((u >> 16) & 1u)) >> 16;
    return (u16)r;
}
__device__ __forceinline__ float bf2f(u16 h) {
    return __uint_as_float(((unsigned)h) << 16);
}
__device__ __forceinline__ unsigned pack2bf(float a, float b) {
    return (unsigned)f2bf(a) | ((unsigned)f2bf(b) << 16);
}

// K0: transpose w_q (k-major fp32) -> BThi (n-major bf16, RTN)
__global__ __launch_bounds__(256) void prepb_kernel(const float* __restrict__ B,
                                                    u16* __restrict__ BThi) {
    int k = blockIdx.x;
    int n = threadIdx.x;
    BThi[n * 256 + k] = f2bf(B[k * 256 + n]);
}

// K1: beta[j,h] = sum_{d<64} x_edge[j, h*64+d] * weight[h, d]
__global__ __launch_bounds__(256) void beta_kernel(const float* __restrict__ xe,
                                                   const float* __restrict__ weight,
                                                   float* __restrict__ beta, int NE) {
    int wid = blockIdx.x * 4 + (threadIdx.x >> 6);
    if (wid >= NE) return;
    int lane = threadIdx.x & 63;
    int h = lane >> 4;
    float4 v = *reinterpret_cast<const float4*>(xe + (size_t)wid * DIM + lane * 4);
    float4 w = *reinterpret_cast<const float4*>(weight + h * 128 + (lane & 15) * 4);
    float p = v.x * w.x + v.y * w.y + v.z * w.z + v.w * w.w;
    p += __shfl_xor(p, 1);
    p += __shfl_xor(p, 2);
    p += __shfl_xor(p, 4);
    p += __shfl_xor(p, 8);
    if ((lane & 15) == 0) beta[(size_t)wid * 4 + h] = p;
}

// K2: xq = x_q @ w_q via bf16 MFMA. A: DIRECT global->reg fragments (no LDS,
// per-wave latency hiding). B: per-step LDS staging (L2-hot, FULL 16KB tile:
// 4 uint4 per thread), swizzled. Fused epilogue: gamma -> ex -> segsum/counts.
// 256 threads = 4 waves, one per 64-col head group. BM=64, BN=256, BK=32.
__global__ __launch_bounds__(256, 3) void gemm_fused_kernel(const float* __restrict__ A,
                                                            const u16* __restrict__ BThi,
                                                            const float* __restrict__ weight,
                                                            const float* __restrict__ beta,
                                                            const int* __restrict__ eids,
                                                            u16* __restrict__ xq_out,
                                                            float* __restrict__ exv,
                                                            float* __restrict__ segsum,
                                                            unsigned* __restrict__ counts,
                                                            int NQ) {
    __shared__ u16 B_s[256 * 32];

    const int t = threadIdx.x;
    const int lane = t & 63;
    const int wc = t >> 6;         // wave = head / 64-col group
    const int lr = lane & 15;
    const int kg = lane >> 4;
    const long brow = (long)blockIdx.x * 64;

    const int b_n = t >> 2, b_c = t & 3;     // B staging geometry (+ i*64 n)

    // per-lane A row pointers (clamped once)
    const float* arow[4];
#pragma unroll
    for (int m = 0; m < 4; ++m) {
        long grow = brow + m * 16 + lr;
        if (grow >= NQ) grow = NQ - 1;
        arow[m] = A + grow * DIM + kg * 8;
    }

    f32x4 acc[4][4];
#pragma unroll
    for (int m = 0; m < 4; ++m)
#pragma unroll
        for (int n = 0; n < 4; ++n) acc[m][n] = (f32x4){0.f, 0.f, 0.f, 0.f};

    for (int k0 = 0; k0 < DIM; k0 += 32) {
        // issue all B staging loads (L2-hot) and A fragment loads up front
        uint4 vb[4];
#pragma unroll
        for (int i = 0; i < 4; ++i) {
            int n = b_n + i * 64;
            vb[i] = *reinterpret_cast<const uint4*>(BThi + n * 256 + k0 + b_c * 8);
        }
        float4 af[4][2];
#pragma unroll
        for (int m = 0; m < 4; ++m) {
            af[m][0] = *reinterpret_cast<const float4*>(arow[m] + k0);
            af[m][1] = *reinterpret_cast<const float4*>(arow[m] + k0 + 4);
        }

        __syncthreads();   // all waves done reading B_s from previous step
#pragma unroll
        for (int i = 0; i < 4; ++i) {
            int n = b_n + i * 64;
            int swz = b_c ^ (n & 3) ^ ((n >> 2) & 3);
            *reinterpret_cast<uint4*>(&B_s[n * 32 + (swz << 3)]) = vb[i];
        }
        __syncthreads();   // B tile visible

        short8 bh[4];
#pragma unroll
        for (int n = 0; n < 4; ++n) {
            int nn = wc * 64 + n * 16 + lr;
            int off = nn * 32 + ((kg ^ (nn & 3) ^ ((nn >> 2) & 3)) << 3);
            bh[n] = *reinterpret_cast<const short8*>(&B_s[off]);
        }
#pragma unroll
        for (int m = 0; m < 4; ++m) {
            // convert this m-tile's A fragment fp32 -> packed bf16x8
            unsigned p0 = pack2bf(af[m][0].x, af[m][0].y);
            unsigned p1 = pack2bf(af[m][0].z, af[m][0].w);
            unsigned p2 = pack2bf(af[m][1].x, af[m][1].y);
            unsigned p3 = pack2bf(af[m][1].z, af[m][1].w);
            uint4 packed = make_uint4(p0, p1, p2, p3);
            short8 ah = *reinterpret_cast<short8*>(&packed);
#pragma unroll
            for (int n = 0; n < 4; ++n)
                acc[m][n] = __builtin_amdgcn_mfma_f32_16x16x32_bf16(ah, bh[n], acc[m][n], 0, 0, 0);
        }
    }

    // epilogue: bf16 xq stores + per-head gamma -> ex -> segsum/counts
    float wv[4];
#pragma unroll
    for (int n = 0; n < 4; ++n) wv[n] = weight[wc * 128 + 64 + n * 16 + lr];

#pragma unroll
    for (int m = 0; m < 4; ++m) {
#pragma unroll
        for (int r = 0; r < 4; ++r) {
            long row = brow + m * 16 + kg * 4 + r;
            bool ok = row < NQ;
            float p = 0.f;
#pragma unroll
            for (int n = 0; n < 4; ++n) {
                float v = acc[m][n][r];
                if (ok) xq_out[row * DIM + wc * 64 + n * 16 + lr] = f2bf(v);
                p = fmaf(v, wv[n], p);
            }
            p += __shfl_xor(p, 1);
            p += __shfl_xor(p, 2);
            p += __shfl_xor(p, 4);
            p += __shfl_xor(p, 8);
            if (ok && lr == 0) {
                int j = eids[row];
                float l = beta[(size_t)j * 4 + wc] + p;
                l = l > 0.f ? l : NEG_SLOPE * l;
                float e = __expf(l);
                exv[row * 4 + wc] = e;
                atomicAdd(&segsum[(size_t)j * 4 + wc], e);
                if (wc == 0) atomicAdd(&counts[j], 1u);
            }
        }
    }
}

// ---- CSR build ----
__global__ __launch_bounds__(256) void scan1_kernel(const unsigned* __restrict__ counts,
                                                    unsigned* __restrict__ offs,
                                                    unsigned* __restrict__ blocksums, int NE) {
    __shared__ unsigned s[256];
    int t = threadIdx.x;
    int base = blockIdx.x * 1024 + t * 4;
    unsigned v[4], sum = 0;
#pragma unroll
    for (int i = 0; i < 4; ++i) {
        v[i] = (base + i < NE) ? counts[base + i] : 0u;
        sum += v[i];
    }
    s[t] = sum;
    __syncthreads();
    for (int off = 1; off < 256; off <<= 1) {
        unsigned y = (t >= off) ? s[t - off] : 0u;
        __syncthreads();
        s[t] += y;
        __syncthreads();
    }
    unsigned excl = s[t] - sum;
#pragma unroll
    for (int i = 0; i < 4; ++i) {
        if (base + i < NE) offs[base + i] = excl;
        excl += v[i];
    }
    if (t == 255) blocksums[blockIdx.x] = s[255];
}

__global__ __launch_bounds__(256) void scan2_kernel(unsigned* __restrict__ blocksums, int NB) {
    __shared__ unsigned s[256];
    int t = threadIdx.x;
    unsigned v = (t < NB) ? blocksums[t] : 0u;
    s[t] = v;
    __syncthreads();
    for (int off = 1; off < 256; off <<= 1) {
        unsigned y = (t >= off) ? s[t - off] : 0u;
        __syncthreads();
        s[t] += y;
        __syncthreads();
    }
    if (t < NB) blocksums[t] = s[t] - v;
}

__global__ __launch_bounds__(256) void scan3_kernel(unsigned* __restrict__ offs,
                                                    const unsigned* __restrict__ blocksums,
                                                    unsigned* __restrict__ cursor, int NE) {
    int t = threadIdx.x;
    int base = blockIdx.x * 1024 + t * 4;
    unsigned add = blocksums[blockIdx.x];
#pragma unroll
    for (int i = 0; i < 4; ++i) {
        if (base + i < NE) {
            unsigned o = offs[base + i] + add;
            offs[base + i] = o;
            cursor[base + i] = o;
        }
    }
}

__global__ __launch_bounds__(256) void fill_kernel(const int* __restrict__ eids,
                                                   unsigned* __restrict__ cursor,
                                                   int* __restrict__ qlist, int NQ) {
    int e = blockIdx.x * blockDim.x + threadIdx.x;
    if (e >= NQ) return;
    int j = eids[e];
    unsigned pos = atomicAdd(&cursor[j], 1u);
    qlist[pos] = e;
}

// gather: out[j,:] = sum_{q in seg(j)} (ex[q,h]/(segsum[j,h]+eps)) * xq_bf16[q,:]
__global__ __launch_bounds__(256) void gather_kernel(const float* __restrict__ exv,
                                                     const float* __restrict__ segsum,
                                                     const unsigned* __restrict__ offs,
                                                     const unsigned* __restrict__ counts,
                                                     const int* __restrict__ qlist,
                                                     const u16* __restrict__ xq,
                                                     float* __restrict__ out, int NE) {
    int j = blockIdx.x * 4 + (threadIdx.x >> 6);
    if (j >= NE) return;
    int lane = threadIdx.x & 63;
    int h = lane >> 4;
    unsigned beg = offs[j];
    unsigned n = counts[j];
    float inv = 1.0f / (segsum[(size_t)j * 4 + h] + 1e-16f);
    float4 a0 = make_float4(0.f, 0.f, 0.f, 0.f);
    float4 a1 = make_float4(0.f, 0.f, 0.f, 0.f);
    unsigned i = 0;
    for (; i + 2 <= n; i += 2) {
        int q0 = qlist[beg + i];
        int q1 = qlist[beg + i + 1];
        float w0 = exv[(size_t)q0 * 4 + h] * inv;
        float w1 = exv[(size_t)q1 * 4 + h] * inv;
        u16x4 v0 = *reinterpret_cast<const u16x4*>(xq + (size_t)q0 * DIM + lane * 4);
        u16x4 v1 = *reinterpret_cast<const u16x4*>(xq + (size_t)q1 * DIM + lane * 4);
        a0.x = fmaf(w0, bf2f(v0.x), a0.x); a1.x = fmaf(w1, bf2f(v1.x), a1.x);
        a0.y = fmaf(w0, bf2f(v0.y), a0.y); a1.y = fmaf(w1, bf2f(v1.y), a1.y);
        a0.z = fmaf(w0, bf2f(v0.z), a0.z); a1.z = fmaf(w1, bf2f(v1.z), a1.z);
        a0.w = fmaf(w0, bf2f(v0.w), a0.w); a1.w = fmaf(w1, bf2f(v1.w), a1.w);
    }
    if (i < n) {
        int q0 = qlist[beg + i];
        float w0 = exv[(size_t)q0 * 4 + h] * inv;
        u16x4 v0 = *reinterpret_cast<const u16x4*>(xq + (size_t)q0 * DIM + lane * 4);
        a0.x = fmaf(w0, bf2f(v0.x), a0.x);
        a0.y = fmaf(w0, bf2f(v0.y), a0.y);
        a0.z = fmaf(w0, bf2f(v0.z), a0.z);
        a0.w = fmaf(w0, bf2f(v0.w), a0.w);
    }
    float4 acc = make_float4(a0.x + a1.x, a0.y + a1.y, a0.z + a1.z, a0.w + a1.w);
    *reinterpret_cast<float4*>(out + (size_t)j * DIM + lane * 4) = acc;
}

extern "C" void kernel_launch(void* const* d_in, const int* in_sizes, int n_in,
                              void* d_out, int out_size, void* d_ws, size_t ws_size,
                              hipStream_t stream) {
    (void)n_in; (void)out_size; (void)ws_size;
    const float* x_q    = (const float*)d_in[0];
    const float* x_edge = (const float*)d_in[1];
    const float* w_q    = (const float*)d_in[2];
    const float* weight = (const float*)d_in[3];
    const int*   eids   = (const int*)d_in[4];
    const int NQ = in_sizes[0] / DIM;   // 500000
    const int NE = in_sizes[1] / DIM;   // 250000
    float* out = (float*)d_out;

    // workspace layout
    u16*      xq        = (u16*)d_ws;                           // NQ*256 bf16
    float*    exv       = (float*)(xq + (size_t)NQ * DIM);      // NQ*4
    float*    beta      = exv + (size_t)NQ * 4;                 // NE*4
    float*    segsum    = beta + (size_t)NE * 4;                // NE*4
    unsigned* counts    = (unsigned*)(segsum + (size_t)NE * 4); // NE
    unsigned* offs      = counts + NE;                          // NE
    unsigned* cursor    = offs + NE;                            // NE
    int*      qlist     = (int*)(cursor + NE);                  // NQ
    unsigned* blocksums = (unsigned*)(qlist + NQ);              // 256
    u16*      BThi      = (u16*)(blocksums + 256);              // 256*256

    const int NB = (NE + 1023) / 1024;

    hipMemsetAsync(segsum, 0, (size_t)NE * 4 * sizeof(float), stream);
    hipMemsetAsync(counts, 0, (size_t)NE * sizeof(unsigned), stream);

    prepb_kernel<<<256, 256, 0, stream>>>(w_q, BThi);
    beta_kernel<<<(NE + 3) / 4, 256, 0, stream>>>(x_edge, weight, beta, NE);
    gemm_fused_kernel<<<(NQ + 63) / 64, 256, 0, stream>>>(x_q, BThi, weight, beta, eids,
                                                          xq, exv, segsum, counts, NQ);
    scan1_kernel<<<NB, 256, 0, stream>>>(counts, offs, blocksums, NE);
    scan2_kernel<<<1, 256, 0, stream>>>(blocksums, NB);
    scan3_kernel<<<NB, 256, 0, stream>>>(offs, blocksums, cursor, NE);
    fill_kernel<<<(NQ + 255) / 256, 256, 0, stream>>>(eids, cursor, qlist, NQ);
    gather_kernel<<<(NE + 3) / 4, 256, 0, stream>>>(exv, segsum, offs, counts, qlist, xq, out, NE);
}

// Round 11
// 735.376 us; speedup vs baseline: 1.3534x; 1.3534x over previous
//
#include <hip/hip_runtime.h>
#include <hip/hip_bf16.h>

#define DIM 256
#define HEADS 4
#define NEG_SLOPE 0.01f

typedef unsigned short u16;
typedef __attribute__((ext_vector_type(8))) short short8;
typedef __attribute__((ext_vector_type(4))) float f32x4;
typedef __attribute__((ext_vector_type(4))) unsigned short u16x4;

// ---- bf16 helpers ----
__device__ __forceinline__ u16 f2bf(float f) {           // RTN-even
    unsigned u = __float_as_uint(f);
    unsigned r = (u + 0x7fffu + ((u >> 16) & 1u)) >> 16;
    return (u16)r;
}
__device__ __forceinline__ float bf2f(u16 h) {
    return __uint_as_float(((unsigned)h) << 16);
}
__device__ __forceinline__ unsigned pack2bf(float a, float b) {
    return (unsigned)f2bf(a) | ((unsigned)f2bf(b) << 16);
}

// K0: transpose w_q (k-major fp32) -> BThi (n-major bf16, RTN)
__global__ __launch_bounds__(256) void prepb_kernel(const float* __restrict__ B,
                                                    u16* __restrict__ BThi) {
    int k = blockIdx.x;
    int n = threadIdx.x;
    BThi[n * 256 + k] = f2bf(B[k * 256 + n]);
}

// K1: beta[j,h] = sum_{d<64} x_edge[j, h*64+d] * weight[h, d]
__global__ __launch_bounds__(256) void beta_kernel(const float* __restrict__ xe,
                                                   const float* __restrict__ weight,
                                                   float* __restrict__ beta, int NE) {
    int wid = blockIdx.x * 4 + (threadIdx.x >> 6);
    if (wid >= NE) return;
    int lane = threadIdx.x & 63;
    int h = lane >> 4;
    float4 v = *reinterpret_cast<const float4*>(xe + (size_t)wid * DIM + lane * 4);
    float4 w = *reinterpret_cast<const float4*>(weight + h * 128 + (lane & 15) * 4);
    float p = v.x * w.x + v.y * w.y + v.z * w.z + v.w * w.w;
    p += __shfl_xor(p, 1);
    p += __shfl_xor(p, 2);
    p += __shfl_xor(p, 4);
    p += __shfl_xor(p, 8);
    if ((lane & 15) == 0) beta[(size_t)wid * 4 + h] = p;
}

// K2: xq = x_q @ w_q via bf16 MFMA — ZERO LDS, ZERO barriers.
// A: direct global->reg (L1-shared across the block's 4 waves).
// B: direct global->reg fragments (128 KB bf16, L2/L3-resident).
// Every wave is an independent stream -> full TLP latency hiding.
// 256 threads = 4 waves, one per 64-col head group. BM=64, BN=256, BK=32.
// Fused epilogue: gamma -> logit -> ex -> exv/segsum/counts.
__global__ __launch_bounds__(256, 2) void gemm_fused_kernel(const float* __restrict__ A,
                                                            const u16* __restrict__ BThi,
                                                            const float* __restrict__ weight,
                                                            const float* __restrict__ beta,
                                                            const int* __restrict__ eids,
                                                            u16* __restrict__ xq_out,
                                                            float* __restrict__ exv,
                                                            float* __restrict__ segsum,
                                                            unsigned* __restrict__ counts,
                                                            int NQ) {
    const int t = threadIdx.x;
    const int lane = t & 63;
    const int wc = t >> 6;         // wave = head / 64-col group
    const int lr = lane & 15;
    const int kg = lane >> 4;
    const long brow = (long)blockIdx.x * 64;

    // per-lane A row pointers (clamped once); offset by kg*8 floats
    const float* arow[4];
#pragma unroll
    for (int m = 0; m < 4; ++m) {
        long grow = brow + m * 16 + lr;
        if (grow >= NQ) grow = NQ - 1;
        arow[m] = A + grow * DIM + kg * 8;
    }
    // per-lane B fragment pointers: row nn = wc*64 + n*16 + lr, col offset kg*8
    const u16* brows[4];
#pragma unroll
    for (int n = 0; n < 4; ++n)
        brows[n] = BThi + (wc * 64 + n * 16 + lr) * 256 + kg * 8;

    f32x4 acc[4][4];
#pragma unroll
    for (int m = 0; m < 4; ++m)
#pragma unroll
        for (int n = 0; n < 4; ++n) acc[m][n] = (f32x4){0.f, 0.f, 0.f, 0.f};

    for (int k0 = 0; k0 < DIM; k0 += 32) {
        // issue all loads for this k-step up front (no fences anywhere)
        short8 bh[4];
#pragma unroll
        for (int n = 0; n < 4; ++n)
            bh[n] = *reinterpret_cast<const short8*>(brows[n] + k0);
        float4 af[4][2];
#pragma unroll
        for (int m = 0; m < 4; ++m) {
            af[m][0] = *reinterpret_cast<const float4*>(arow[m] + k0);
            af[m][1] = *reinterpret_cast<const float4*>(arow[m] + k0 + 4);
        }
#pragma unroll
        for (int m = 0; m < 4; ++m) {
            unsigned p0 = pack2bf(af[m][0].x, af[m][0].y);
            unsigned p1 = pack2bf(af[m][0].z, af[m][0].w);
            unsigned p2 = pack2bf(af[m][1].x, af[m][1].y);
            unsigned p3 = pack2bf(af[m][1].z, af[m][1].w);
            uint4 packed = make_uint4(p0, p1, p2, p3);
            short8 ah = *reinterpret_cast<short8*>(&packed);
#pragma unroll
            for (int n = 0; n < 4; ++n)
                acc[m][n] = __builtin_amdgcn_mfma_f32_16x16x32_bf16(ah, bh[n], acc[m][n], 0, 0, 0);
        }
    }

    // epilogue: bf16 xq stores + per-head gamma -> ex -> segsum/counts
    float wv[4];
#pragma unroll
    for (int n = 0; n < 4; ++n) wv[n] = weight[wc * 128 + 64 + n * 16 + lr];

#pragma unroll
    for (int m = 0; m < 4; ++m) {
#pragma unroll
        for (int r = 0; r < 4; ++r) {
            long row = brow + m * 16 + kg * 4 + r;
            bool ok = row < NQ;
            float p = 0.f;
#pragma unroll
            for (int n = 0; n < 4; ++n) {
                float v = acc[m][n][r];
                if (ok) xq_out[row * DIM + wc * 64 + n * 16 + lr] = f2bf(v);
                p = fmaf(v, wv[n], p);
            }
            p += __shfl_xor(p, 1);
            p += __shfl_xor(p, 2);
            p += __shfl_xor(p, 4);
            p += __shfl_xor(p, 8);
            if (ok && lr == 0) {
                int j = eids[row];
                float l = beta[(size_t)j * 4 + wc] + p;
                l = l > 0.f ? l : NEG_SLOPE * l;
                float e = __expf(l);
                exv[row * 4 + wc] = e;
                atomicAdd(&segsum[(size_t)j * 4 + wc], e);
                if (wc == 0) atomicAdd(&counts[j], 1u);
            }
        }
    }
}

// ---- CSR build ----
__global__ __launch_bounds__(256) void scan1_kernel(const unsigned* __restrict__ counts,
                                                    unsigned* __restrict__ offs,
                                                    unsigned* __restrict__ blocksums, int NE) {
    __shared__ unsigned s[256];
    int t = threadIdx.x;
    int base = blockIdx.x * 1024 + t * 4;
    unsigned v[4], sum = 0;
#pragma unroll
    for (int i = 0; i < 4; ++i) {
        v[i] = (base + i < NE) ? counts[base + i] : 0u;
        sum += v[i];
    }
    s[t] = sum;
    __syncthreads();
    for (int off = 1; off < 256; off <<= 1) {
        unsigned y = (t >= off) ? s[t - off] : 0u;
        __syncthreads();
        s[t] += y;
        __syncthreads();
    }
    unsigned excl = s[t] - sum;
#pragma unroll
    for (int i = 0; i < 4; ++i) {
        if (base + i < NE) offs[base + i] = excl;
        excl += v[i];
    }
    if (t == 255) blocksums[blockIdx.x] = s[255];
}

__global__ __launch_bounds__(256) void scan2_kernel(unsigned* __restrict__ blocksums, int NB) {
    __shared__ unsigned s[256];
    int t = threadIdx.x;
    unsigned v = (t < NB) ? blocksums[t] : 0u;
    s[t] = v;
    __syncthreads();
    for (int off = 1; off < 256; off <<= 1) {
        unsigned y = (t >= off) ? s[t - off] : 0u;
        __syncthreads();
        s[t] += y;
        __syncthreads();
    }
    if (t < NB) blocksums[t] = s[t] - v;
}

__global__ __launch_bounds__(256) void scan3_kernel(unsigned* __restrict__ offs,
                                                    const unsigned* __restrict__ blocksums,
                                                    unsigned* __restrict__ cursor, int NE) {
    int t = threadIdx.x;
    int base = blockIdx.x * 1024 + t * 4;
    unsigned add = blocksums[blockIdx.x];
#pragma unroll
    for (int i = 0; i < 4; ++i) {
        if (base + i < NE) {
            unsigned o = offs[base + i] + add;
            offs[base + i] = o;
            cursor[base + i] = o;
        }
    }
}

__global__ __launch_bounds__(256) void fill_kernel(const int* __restrict__ eids,
                                                   unsigned* __restrict__ cursor,
                                                   int* __restrict__ qlist, int NQ) {
    int e = blockIdx.x * blockDim.x + threadIdx.x;
    if (e >= NQ) return;
    int j = eids[e];
    unsigned pos = atomicAdd(&cursor[j], 1u);
    qlist[pos] = e;
}

// gather: out[j,:] = sum_{q in seg(j)} (ex[q,h]/(segsum[j,h]+eps)) * xq_bf16[q,:]
__global__ __launch_bounds__(256) void gather_kernel(const float* __restrict__ exv,
                                                     const float* __restrict__ segsum,
                                                     const unsigned* __restrict__ offs,
                                                     const unsigned* __restrict__ counts,
                                                     const int* __restrict__ qlist,
                                                     const u16* __restrict__ xq,
                                                     float* __restrict__ out, int NE) {
    int j = blockIdx.x * 4 + (threadIdx.x >> 6);
    if (j >= NE) return;
    int lane = threadIdx.x & 63;
    int h = lane >> 4;
    unsigned beg = offs[j];
    unsigned n = counts[j];
    float inv = 1.0f / (segsum[(size_t)j * 4 + h] + 1e-16f);
    float4 a0 = make_float4(0.f, 0.f, 0.f, 0.f);
    float4 a1 = make_float4(0.f, 0.f, 0.f, 0.f);
    unsigned i = 0;
    for (; i + 2 <= n; i += 2) {
        int q0 = qlist[beg + i];
        int q1 = qlist[beg + i + 1];
        float w0 = exv[(size_t)q0 * 4 + h] * inv;
        float w1 = exv[(size_t)q1 * 4 + h] * inv;
        u16x4 v0 = *reinterpret_cast<const u16x4*>(xq + (size_t)q0 * DIM + lane * 4);
        u16x4 v1 = *reinterpret_cast<const u16x4*>(xq + (size_t)q1 * DIM + lane * 4);
        a0.x = fmaf(w0, bf2f(v0.x), a0.x); a1.x = fmaf(w1, bf2f(v1.x), a1.x);
        a0.y = fmaf(w0, bf2f(v0.y), a0.y); a1.y = fmaf(w1, bf2f(v1.y), a1.y);
        a0.z = fmaf(w0, bf2f(v0.z), a0.z); a1.z = fmaf(w1, bf2f(v1.z), a1.z);
        a0.w = fmaf(w0, bf2f(v0.w), a0.w); a1.w = fmaf(w1, bf2f(v1.w), a1.w);
    }
    if (i < n) {
        int q0 = qlist[beg + i];
        float w0 = exv[(size_t)q0 * 4 + h] * inv;
        u16x4 v0 = *reinterpret_cast<const u16x4*>(xq + (size_t)q0 * DIM + lane * 4);
        a0.x = fmaf(w0, bf2f(v0.x), a0.x);
        a0.y = fmaf(w0, bf2f(v0.y), a0.y);
        a0.z = fmaf(w0, bf2f(v0.z), a0.z);
        a0.w = fmaf(w0, bf2f(v0.w), a0.w);
    }
    float4 acc = make_float4(a0.x + a1.x, a0.y + a1.y, a0.z + a1.z, a0.w + a1.w);
    *reinterpret_cast<float4*>(out + (size_t)j * DIM + lane * 4) = acc;
}

extern "C" void kernel_launch(void* const* d_in, const int* in_sizes, int n_in,
                              void* d_out, int out_size, void* d_ws, size_t ws_size,
                              hipStream_t stream) {
    (void)n_in; (void)out_size; (void)ws_size;
    const float* x_q    = (const float*)d_in[0];
    const float* x_edge = (const float*)d_in[1];
    const float* w_q    = (const float*)d_in[2];
    const float* weight = (const float*)d_in[3];
    const int*   eids   = (const int*)d_in[4];
    const int NQ = in_sizes[0] / DIM;   // 500000
    const int NE = in_sizes[1] / DIM;   // 250000
    float* out = (float*)d_out;

    // workspace layout
    u16*      xq        = (u16*)d_ws;                           // NQ*256 bf16
    float*    exv       = (float*)(xq + (size_t)NQ * DIM);      // NQ*4
    float*    beta      = exv + (size_t)NQ * 4;                 // NE*4
    float*    segsum    = beta + (size_t)NE * 4;                // NE*4
    unsigned* counts    = (unsigned*)(segsum + (size_t)NE * 4); // NE
    unsigned* offs      = counts + NE;                          // NE
    unsigned* cursor    = offs + NE;                            // NE
    int*      qlist     = (int*)(cursor + NE);                  // NQ
    unsigned* blocksums = (unsigned*)(qlist + NQ);              // 256
    u16*      BThi      = (u16*)(blocksums + 256);              // 256*256

    const int NB = (NE + 1023) / 1024;

    hipMemsetAsync(segsum, 0, (size_t)NE * 4 * sizeof(float), stream);
    hipMemsetAsync(counts, 0, (size_t)NE * sizeof(unsigned), stream);

    prepb_kernel<<<256, 256, 0, stream>>>(w_q, BThi);
    beta_kernel<<<(NE + 3) / 4, 256, 0, stream>>>(x_edge, weight, beta, NE);
    gemm_fused_kernel<<<(NQ + 63) / 64, 256, 0, stream>>>(x_q, BThi, weight, beta, eids,
                                                          xq, exv, segsum, counts, NQ);
    scan1_kernel<<<NB, 256, 0, stream>>>(counts, offs, blocksums, NE);
    scan2_kernel<<<1, 256, 0, stream>>>(blocksums, NB);
    scan3_kernel<<<NB, 256, 0, stream>>>(offs, blocksums, cursor, NE);
    fill_kernel<<<(NQ + 255) / 256, 256, 0, stream>>>(eids, cursor, qlist, NQ);
    gather_kernel<<<(NE + 3) / 4, 256, 0, stream>>>(exv, segsum, offs, counts, qlist, xq, out, NE);
}

// Round 12
// 561.904 us; speedup vs baseline: 1.7712x; 1.3087x over previous
//
#include <hip/hip_runtime.h>
#include <hip/hip_bf16.h>

#define DIM 256
#define HEADS 4
#define NEG_SLOPE 0.01f

typedef unsigned short u16;
typedef __attribute__((ext_vector_type(8))) short short8;
typedef __attribute__((ext_vector_type(4))) float f32x4;
typedef __attribute__((ext_vector_type(4))) unsigned short u16x4;

// ---- bf16 helpers ----
__device__ __forceinline__ u16 f2bf(float f) {           // RTN-even
    unsigned u = __float_as_uint(f);
    unsigned r = (u + 0x7fffu + ((u >> 16) & 1u)) >> 16;
    return (u16)r;
}
__device__ __forceinline__ float bf2f(u16 h) {
    return __uint_as_float(((unsigned)h) << 16);
}

// K0: transpose w_q (k-major fp32) -> BThi (n-major bf16, RTN)
__global__ __launch_bounds__(256) void prepb_kernel(const float* __restrict__ B,
                                                    u16* __restrict__ BThi) {
    int k = blockIdx.x;
    int n = threadIdx.x;
    BThi[n * 256 + k] = f2bf(B[k * 256 + n]);
}

// K1: beta[j,h] = sum_{d<64} x_edge[j, h*64+d] * weight[h, d]
__global__ __launch_bounds__(256) void beta_kernel(const float* __restrict__ xe,
                                                   const float* __restrict__ weight,
                                                   float* __restrict__ beta, int NE) {
    int wid = blockIdx.x * 4 + (threadIdx.x >> 6);
    if (wid >= NE) return;
    int lane = threadIdx.x & 63;
    int h = lane >> 4;
    float4 v = *reinterpret_cast<const float4*>(xe + (size_t)wid * DIM + lane * 4);
    float4 w = *reinterpret_cast<const float4*>(weight + h * 128 + (lane & 15) * 4);
    float p = v.x * w.x + v.y * w.y + v.z * w.z + v.w * w.w;
    p += __shfl_xor(p, 1);
    p += __shfl_xor(p, 2);
    p += __shfl_xor(p, 4);
    p += __shfl_xor(p, 8);
    if ((lane & 15) == 0) beta[(size_t)wid * 4 + h] = p;
}

// K2: xq = x_q @ w_q via bf16 MFMA.
// A: LDS, double-buffered, reg-staged (2 float4/thread), converted once/block.
// B: direct global->reg fragments (128 KB bf16, L2-resident, coalesced).
// ONE barrier per k-step (dbuf). Fused epilogue: gamma -> ex -> segsum/counts.
// 256 threads = 4 waves, one per 64-col head group. BM=64, BN=256, BK=32.
__global__ __launch_bounds__(256, 3) void gemm_fused_kernel(const float* __restrict__ A,
                                                            const u16* __restrict__ BThi,
                                                            const float* __restrict__ weight,
                                                            const float* __restrict__ beta,
                                                            const int* __restrict__ eids,
                                                            u16* __restrict__ xq_out,
                                                            float* __restrict__ exv,
                                                            float* __restrict__ segsum,
                                                            unsigned* __restrict__ counts,
                                                            int NQ) {
    __shared__ u16 A_s[2][64 * 32];   // 8 KB

    const int t = threadIdx.x;
    const int lane = t & 63;
    const int wc = t >> 6;         // wave = head / 64-col group
    const int lr = lane & 15;
    const int kg = lane >> 4;
    const long brow = (long)blockIdx.x * 64;

    // A staging geometry: thread covers 2 slots (rows 0-31, 32-63), 1 float4 each
    const int s_row0 = t >> 3, s_c4 = t & 7;
    const float* aptr0;
    const float* aptr1;
    {
        long g0 = brow + s_row0;       if (g0 >= NQ) g0 = NQ - 1;
        long g1 = brow + s_row0 + 32;  if (g1 >= NQ) g1 = NQ - 1;
        aptr0 = A + g0 * DIM + s_c4 * 4;
        aptr1 = A + g1 * DIM + s_c4 * 4;
    }
    // B fragment pointers (direct from L2)
    const u16* brows[4];
#pragma unroll
    for (int n = 0; n < 4; ++n)
        brows[n] = BThi + (wc * 64 + n * 16 + lr) * 256 + kg * 8;

    f32x4 acc[4][4];
#pragma unroll
    for (int m = 0; m < 4; ++m)
#pragma unroll
        for (int n = 0; n < 4; ++n) acc[m][n] = (f32x4){0.f, 0.f, 0.f, 0.f};

    float4 a_reg0, a_reg1;
    auto load_a = [&](int k0) {
        a_reg0 = *reinterpret_cast<const float4*>(aptr0 + k0);
        a_reg1 = *reinterpret_cast<const float4*>(aptr1 + k0);
    };
    auto write_a = [&](int buf) {
#pragma unroll
        for (int i = 0; i < 2; ++i) {
            int row = s_row0 + i * 32;
            float4 v = i ? a_reg1 : a_reg0;
            u16x4 hv;
            hv.x = f2bf(v.x); hv.y = f2bf(v.y); hv.z = f2bf(v.z); hv.w = f2bf(v.w);
            int swz = (s_c4 >> 1) ^ (row & 3) ^ ((row >> 2) & 3);
            int off = row * 32 + (swz << 3) + ((s_c4 & 1) << 2);
            *reinterpret_cast<u16x4*>(&A_s[buf][off]) = hv;
        }
    };

    load_a(0);
    write_a(0);
    __syncthreads();

    for (int step = 0; step < 8; ++step) {
        const int buf = step & 1;
        const int k0 = step * 32;
        if (step < 7) load_a(k0 + 32);       // issue next A loads early (hide HBM)

        short8 bh[4];
#pragma unroll
        for (int n = 0; n < 4; ++n)
            bh[n] = *reinterpret_cast<const short8*>(brows[n] + k0);

#pragma unroll
        for (int m = 0; m < 4; ++m) {
            int rr = m * 16 + lr;
            int off = rr * 32 + ((kg ^ (rr & 3) ^ ((rr >> 2) & 3)) << 3);
            short8 ah = *reinterpret_cast<const short8*>(&A_s[buf][off]);
#pragma unroll
            for (int n = 0; n < 4; ++n)
                acc[m][n] = __builtin_amdgcn_mfma_f32_16x16x32_bf16(ah, bh[n], acc[m][n], 0, 0, 0);
        }

        if (step < 7) {
            write_a(buf ^ 1);    // waits on a_reg vmcnt; writes the other buffer
            __syncthreads();     // single barrier per k-step (dbuf-safe)
        }
    }

    // epilogue: bf16 xq stores + per-head gamma -> ex -> segsum/counts
    float wv[4];
#pragma unroll
    for (int n = 0; n < 4; ++n) wv[n] = weight[wc * 128 + 64 + n * 16 + lr];

#pragma unroll
    for (int m = 0; m < 4; ++m) {
#pragma unroll
        for (int r = 0; r < 4; ++r) {
            long row = brow + m * 16 + kg * 4 + r;
            bool ok = row < NQ;
            float p = 0.f;
#pragma unroll
            for (int n = 0; n < 4; ++n) {
                float v = acc[m][n][r];
                if (ok) xq_out[row * DIM + wc * 64 + n * 16 + lr] = f2bf(v);
                p = fmaf(v, wv[n], p);
            }
            p += __shfl_xor(p, 1);
            p += __shfl_xor(p, 2);
            p += __shfl_xor(p, 4);
            p += __shfl_xor(p, 8);
            if (ok && lr == 0) {
                int j = eids[row];
                float l = beta[(size_t)j * 4 + wc] + p;
                l = l > 0.f ? l : NEG_SLOPE * l;
                float e = __expf(l);
                exv[row * 4 + wc] = e;
                atomicAdd(&segsum[(size_t)j * 4 + wc], e);
                if (wc == 0) atomicAdd(&counts[j], 1u);
            }
        }
    }
}

// ---- CSR build ----
__global__ __launch_bounds__(256) void scan1_kernel(const unsigned* __restrict__ counts,
                                                    unsigned* __restrict__ offs,
                                                    unsigned* __restrict__ blocksums, int NE) {
    __shared__ unsigned s[256];
    int t = threadIdx.x;
    int base = blockIdx.x * 1024 + t * 4;
    unsigned v[4], sum = 0;
#pragma unroll
    for (int i = 0; i < 4; ++i) {
        v[i] = (base + i < NE) ? counts[base + i] : 0u;
        sum += v[i];
    }
    s[t] = sum;
    __syncthreads();
    for (int off = 1; off < 256; off <<= 1) {
        unsigned y = (t >= off) ? s[t - off] : 0u;
        __syncthreads();
        s[t] += y;
        __syncthreads();
    }
    unsigned excl = s[t] - sum;
#pragma unroll
    for (int i = 0; i < 4; ++i) {
        if (base + i < NE) offs[base + i] = excl;
        excl += v[i];
    }
    if (t == 255) blocksums[blockIdx.x] = s[255];
}

__global__ __launch_bounds__(256) void scan2_kernel(unsigned* __restrict__ blocksums, int NB) {
    __shared__ unsigned s[256];
    int t = threadIdx.x;
    unsigned v = (t < NB) ? blocksums[t] : 0u;
    s[t] = v;
    __syncthreads();
    for (int off = 1; off < 256; off <<= 1) {
        unsigned y = (t >= off) ? s[t - off] : 0u;
        __syncthreads();
        s[t] += y;
        __syncthreads();
    }
    if (t < NB) blocksums[t] = s[t] - v;
}

__global__ __launch_bounds__(256) void scan3_kernel(unsigned* __restrict__ offs,
                                                    const unsigned* __restrict__ blocksums,
                                                    unsigned* __restrict__ cursor, int NE) {
    int t = threadIdx.x;
    int base = blockIdx.x * 1024 + t * 4;
    unsigned add = blocksums[blockIdx.x];
#pragma unroll
    for (int i = 0; i < 4; ++i) {
        if (base + i < NE) {
            unsigned o = offs[base + i] + add;
            offs[base + i] = o;
            cursor[base + i] = o;
        }
    }
}

__global__ __launch_bounds__(256) void fill_kernel(const int* __restrict__ eids,
                                                   unsigned* __restrict__ cursor,
                                                   int* __restrict__ qlist, int NQ) {
    int e = blockIdx.x * blockDim.x + threadIdx.x;
    if (e >= NQ) return;
    int j = eids[e];
    unsigned pos = atomicAdd(&cursor[j], 1u);
    qlist[pos] = e;
}

// gather: out[j,:] = sum_{q in seg(j)} (ex[q,h]/(segsum[j,h]+eps)) * xq_bf16[q,:]
__global__ __launch_bounds__(256) void gather_kernel(const float* __restrict__ exv,
                                                     const float* __restrict__ segsum,
                                                     const unsigned* __restrict__ offs,
                                                     const unsigned* __restrict__ counts,
                                                     const int* __restrict__ qlist,
                                                     const u16* __restrict__ xq,
                                                     float* __restrict__ out, int NE) {
    int j = blockIdx.x * 4 + (threadIdx.x >> 6);
    if (j >= NE) return;
    int lane = threadIdx.x & 63;
    int h = lane >> 4;
    unsigned beg = offs[j];
    unsigned n = counts[j];
    float inv = 1.0f / (segsum[(size_t)j * 4 + h] + 1e-16f);
    float4 a0 = make_float4(0.f, 0.f, 0.f, 0.f);
    float4 a1 = make_float4(0.f, 0.f, 0.f, 0.f);
    unsigned i = 0;
    for (; i + 2 <= n; i += 2) {
        int q0 = qlist[beg + i];
        int q1 = qlist[beg + i + 1];
        float w0 = exv[(size_t)q0 * 4 + h] * inv;
        float w1 = exv[(size_t)q1 * 4 + h] * inv;
        u16x4 v0 = *reinterpret_cast<const u16x4*>(xq + (size_t)q0 * DIM + lane * 4);
        u16x4 v1 = *reinterpret_cast<const u16x4*>(xq + (size_t)q1 * DIM + lane * 4);
        a0.x = fmaf(w0, bf2f(v0.x), a0.x); a1.x = fmaf(w1, bf2f(v1.x), a1.x);
        a0.y = fmaf(w0, bf2f(v0.y), a0.y); a1.y = fmaf(w1, bf2f(v1.y), a1.y);
        a0.z = fmaf(w0, bf2f(v0.z), a0.z); a1.z = fmaf(w1, bf2f(v1.z), a1.z);
        a0.w = fmaf(w0, bf2f(v0.w), a0.w); a1.w = fmaf(w1, bf2f(v1.w), a1.w);
    }
    if (i < n) {
        int q0 = qlist[beg + i];
        float w0 = exv[(size_t)q0 * 4 + h] * inv;
        u16x4 v0 = *reinterpret_cast<const u16x4*>(xq + (size_t)q0 * DIM + lane * 4);
        a0.x = fmaf(w0, bf2f(v0.x), a0.x);
        a0.y = fmaf(w0, bf2f(v0.y), a0.y);
        a0.z = fmaf(w0, bf2f(v0.z), a0.z);
        a0.w = fmaf(w0, bf2f(v0.w), a0.w);
    }
    float4 acc = make_float4(a0.x + a1.x, a0.y + a1.y, a0.z + a1.z, a0.w + a1.w);
    *reinterpret_cast<float4*>(out + (size_t)j * DIM + lane * 4) = acc;
}

extern "C" void kernel_launch(void* const* d_in, const int* in_sizes, int n_in,
                              void* d_out, int out_size, void* d_ws, size_t ws_size,
                              hipStream_t stream) {
    (void)n_in; (void)out_size; (void)ws_size;
    const float* x_q    = (const float*)d_in[0];
    const float* x_edge = (const float*)d_in[1];
    const float* w_q    = (const float*)d_in[2];
    const float* weight = (const float*)d_in[3];
    const int*   eids   = (const int*)d_in[4];
    const int NQ = in_sizes[0] / DIM;   // 500000
    const int NE = in_sizes[1] / DIM;   // 250000
    float* out = (float*)d_out;

    // workspace layout
    u16*      xq        = (u16*)d_ws;                           // NQ*256 bf16
    float*    exv       = (float*)(xq + (size_t)NQ * DIM);      // NQ*4
    float*    beta      = exv + (size_t)NQ * 4;                 // NE*4
    float*    segsum    = beta + (size_t)NE * 4;                // NE*4
    unsigned* counts    = (unsigned*)(segsum + (size_t)NE * 4); // NE
    unsigned* offs      = counts + NE;                          // NE
    unsigned* cursor    = offs + NE;                            // NE
    int*      qlist     = (int*)(cursor + NE);                  // NQ
    unsigned* blocksums = (unsigned*)(qlist + NQ);              // 256
    u16*      BThi      = (u16*)(blocksums + 256);              // 256*256

    const int NB = (NE + 1023) / 1024;

    hipMemsetAsync(segsum, 0, (size_t)NE * 4 * sizeof(float), stream);
    hipMemsetAsync(counts, 0, (size_t)NE * sizeof(unsigned), stream);

    prepb_kernel<<<256, 256, 0, stream>>>(w_q, BThi);
    beta_kernel<<<(NE + 3) / 4, 256, 0, stream>>>(x_edge, weight, beta, NE);
    gemm_fused_kernel<<<(NQ + 63) / 64, 256, 0, stream>>>(x_q, BThi, weight, beta, eids,
                                                          xq, exv, segsum, counts, NQ);
    scan1_kernel<<<NB, 256, 0, stream>>>(counts, offs, blocksums, NE);
    scan2_kernel<<<1, 256, 0, stream>>>(blocksums, NB);
    scan3_kernel<<<NB, 256, 0, stream>>>(offs, blocksums, cursor, NE);
    fill_kernel<<<(NQ + 255) / 256, 256, 0, stream>>>(eids, cursor, qlist, NQ);
    gather_kernel<<<(NE + 3) / 4, 256, 0, stream>>>(exv, segsum, offs, counts, qlist, xq, out, NE);
}